// Round 3
// baseline (463.164 us; speedup 1.0000x reference)
//
#include <hip/hip_runtime.h>
#include <hip/hip_bf16.h>

// GroupedMLP: E=8, H=1024, I=2816, T=8192. fp32 in HBM, bf16 MFMA compute.
//   1) prep_k:  fused convx (X fp32->bf16) + tconvGU (gate/up fp32 [E,H,I] -> bf16 [E,I,H])
//   2) gemm12:  inter = silu(xb@gate)*(xb@up)  [BK=64, chunk-swizzled; ~880 TF ANCHOR - frozen]
//   3) gemm3:   out = inter @ down, BM=128 BN=128 BK=64, double-buffered.
//               NEW: no tconvD — B (down fp32 [I,H]) is reg-staged per K-tile with dense
//               float2 loads, converted to bf16 in-register, ds_write_b128 into the SAME
//               chunk-swizzled LDS layout as before (fragment-read path unchanged).
//               NEW: XCD-aware block swizzle (each XCD = 8M x 8N super-tile for L2 reuse).
// Chunk swizzle (GEMM LDS): 16B-chunk for (row r, k-chunk j) lives at r*8 + (j ^ (r&7)).
// ws: 3 x 46,137,344 B (gateT, upT, inter).

#define E_ 8
#define H_ 1024
#define I_ 2816
#define T_ 8192

typedef unsigned short u16;
typedef __attribute__((ext_vector_type(4))) unsigned short u16x4;
typedef __attribute__((ext_vector_type(8))) short s16x8;
typedef __attribute__((ext_vector_type(8))) unsigned short u16x8;
typedef __attribute__((ext_vector_type(4))) float f32x4;

__device__ __forceinline__ void async16(const u16* g, u16* l) {
  __builtin_amdgcn_global_load_lds((__attribute__((address_space(1))) void*)g,
                                   (__attribute__((address_space(3))) void*)l, 16, 0, 0);
}

__device__ __forceinline__ u16 f2b(float f) {
  union { __hip_bfloat16 h; u16 u; } c;
  c.h = __float2bfloat16(f);
  return c.u;
}

// ---- dense transpose+convert: out[c][r] bf16 = in[r][c] fp32, 64x64 tile ----
template <int R, int C>
__device__ __forceinline__ void tconv_tile(const float* __restrict__ in,
                                           u16* __restrict__ out,
                                           int bx, int by, int t) {
  __shared__ u16 lt[64 * 68];
  const int c0 = bx * 64, r0 = by * 64;

  const int cQ = (t & 15) * 4;
  const int rB = (t >> 4) * 4;
  const float* p = in + (size_t)(r0 + rB) * C + (c0 + cQ);
  float4 v[4];
#pragma unroll
  for (int j = 0; j < 4; ++j) v[j] = *(const float4*)(p + (size_t)j * C);
  const float* vf = (const float*)v;  // vf[j*4+q] = elem (rB+j, cQ+q)
#pragma unroll
  for (int q = 0; q < 4; ++q) {
    u16x4 w;
    w[0] = f2b(vf[0 * 4 + q]);
    w[1] = f2b(vf[1 * 4 + q]);
    w[2] = f2b(vf[2 * 4 + q]);
    w[3] = f2b(vf[3 * 4 + q]);
    *(u16x4*)(lt + (cQ + q) * 68 + rB) = w;
  }
  __syncthreads();

  const int c = t >> 2;
  const int rs = (t & 3) * 16;
  const u16* rp = lt + c * 68 + rs;
  u16x4 b0 = *(const u16x4*)(rp);
  u16x4 b1 = *(const u16x4*)(rp + 4);
  u16x4 b2 = *(const u16x4*)(rp + 8);
  u16x4 b3 = *(const u16x4*)(rp + 12);
  u16x8 o0 = __builtin_shufflevector(b0, b1, 0, 1, 2, 3, 4, 5, 6, 7);
  u16x8 o1 = __builtin_shufflevector(b2, b3, 0, 1, 2, 3, 4, 5, 6, 7);
  u16* op = out + (size_t)(c0 + c) * R + (r0 + rs);
  *(u16x8*)(op) = o0;
  *(u16x8*)(op + 8) = o1;
}

// ---------------- fused prep: convx (4096 blocks) + tconvGU (11264 blocks) ----------------
__global__ __launch_bounds__(256) void prep_k(const float* __restrict__ X,
                                              const float* __restrict__ G,
                                              const float* __restrict__ U,
                                              u16* __restrict__ xb,
                                              u16* __restrict__ GT,
                                              u16* __restrict__ UT) {
  const int bid = blockIdx.x;
  const int t = threadIdx.x;
  if (bid < 4096) {
    size_t i = ((size_t)bid * 256 + t) * 8;
    float4 v0 = *(const float4*)(X + i);
    float4 v1 = *(const float4*)(X + i + 4);
    u16x8 b;
    b[0] = f2b(v0.x); b[1] = f2b(v0.y); b[2] = f2b(v0.z); b[3] = f2b(v0.w);
    b[4] = f2b(v1.x); b[5] = f2b(v1.y); b[6] = f2b(v1.z); b[7] = f2b(v1.w);
    *(u16x8*)(xb + i) = b;
  } else {
    int b = bid - 4096;
    const int bx = b % 44; b /= 44;   // I tile
    const int by = b % 16; b /= 16;   // H tile
    const int z = b;                  // expert*2 + (gate/up)
    const size_t eoff = (size_t)(z >> 1) * (size_t)H_ * I_;
    const float* in = ((z & 1) ? U : G) + eoff;
    u16* out = ((z & 1) ? UT : GT) + eoff;
    tconv_tile<H_, I_>(in, out, bx, by, t);
  }
}

// ---------------- fused gate/up GEMM + SwiGLU, BK=64, chunk-swizzled (ANCHOR, frozen) ----------------
__global__ __launch_bounds__(256, 2) void gemm12_k(
    const u16* __restrict__ X, const u16* __restrict__ GT,
    const u16* __restrict__ UT, const int* __restrict__ tpe,
    u16* __restrict__ inter) {
  __shared__ u16 sA[128 * 64];
  __shared__ u16 sG[64 * 64];
  __shared__ u16 sU[64 * 64];
  const int t = threadIdx.x;
  const int m0 = blockIdx.y * 128;
  const int n0 = blockIdx.x * 64;

  int e = 0, seg_end = T_;
  {
    int s = 0;
    for (int i = 0; i < E_; ++i) {
      int c = tpe[i];
      if (m0 < s + c) { e = i; seg_end = s + c; break; }
      s += c;
    }
  }
  const u16* GTe = GT + (size_t)e * I_ * H_;
  const u16* UTe = UT + (size_t)e * I_ * H_;

  const int sj = ((t & 7) ^ ((t >> 3) & 7)) * 8;
  const u16* gA = X + (size_t)(m0 + (t >> 3)) * H_ + sj;
  const u16* gG = GTe + (size_t)(n0 + (t >> 3)) * H_ + sj;
  const u16* gU = UTe + (size_t)(n0 + (t >> 3)) * H_ + sj;
  u16* lA = sA + t * 8;
  u16* lG = sG + t * 8;
  u16* lU = sU + t * 8;

  const int l = t & 63, w = t >> 6;
  const int wm = (w & 1) * 64, wn = (w >> 1) * 32;
  const int c0 = (((l >> 4) ^ (l & 7))) * 8;
  const u16* fA = sA + (size_t)(wm + (l & 15)) * 64;
  const u16* fG = sG + (size_t)(wn + (l & 15)) * 64;
  const u16* fU = sU + (size_t)(wn + (l & 15)) * 64;

  f32x4 accG[4][2], accU[4][2];
#pragma unroll
  for (int mi = 0; mi < 4; ++mi)
#pragma unroll
    for (int ni = 0; ni < 2; ++ni) {
      accG[mi][ni] = (f32x4){0.f, 0.f, 0.f, 0.f};
      accU[mi][ni] = (f32x4){0.f, 0.f, 0.f, 0.f};
    }

  for (int k0 = 0; k0 < H_; k0 += 64) {
    async16(gA + k0, lA);
    async16(gA + 32 * H_ + k0, lA + 2048);
    async16(gA + 64 * H_ + k0, lA + 4096);
    async16(gA + 96 * H_ + k0, lA + 6144);
    async16(gG + k0, lG);
    async16(gG + 32 * H_ + k0, lG + 2048);
    async16(gU + k0, lU);
    async16(gU + 32 * H_ + k0, lU + 2048);
    __syncthreads();
#pragma unroll
    for (int ks = 0; ks < 2; ++ks) {
      const int co = c0 ^ (ks * 32);
      s16x8 aF[4], gF[2], uF[2];
#pragma unroll
      for (int mi = 0; mi < 4; ++mi) aF[mi] = *(const s16x8*)(fA + mi * 1024 + co);
#pragma unroll
      for (int ni = 0; ni < 2; ++ni) {
        gF[ni] = *(const s16x8*)(fG + ni * 1024 + co);
        uF[ni] = *(const s16x8*)(fU + ni * 1024 + co);
      }
#pragma unroll
      for (int mi = 0; mi < 4; ++mi)
#pragma unroll
        for (int ni = 0; ni < 2; ++ni) {
          accG[mi][ni] = __builtin_amdgcn_mfma_f32_16x16x32_bf16(aF[mi], gF[ni], accG[mi][ni], 0, 0, 0);
          accU[mi][ni] = __builtin_amdgcn_mfma_f32_16x16x32_bf16(aF[mi], uF[ni], accU[mi][ni], 0, 0, 0);
        }
    }
    __syncthreads();
  }

  const int colb = l & 15, rowb = (l >> 4) * 4;
#pragma unroll
  for (int mi = 0; mi < 4; ++mi)
#pragma unroll
    for (int ni = 0; ni < 2; ++ni) {
      const size_t gcol = (size_t)(n0 + wn + ni * 16 + colb);
#pragma unroll
      for (int r = 0; r < 4; ++r) {
        int grow = m0 + wm + mi * 16 + rowb + r;
        if (grow < seg_end) {
          float o1 = accG[mi][ni][r];
          float o2 = accU[mi][ni][r];
          float sv = o1 / (1.f + __expf(-o1));
          inter[(size_t)grow * I_ + gcol] = f2b(sv * o2);
        }
      }
    }
}

// ------- down-proj GEMM: BM=128, BN=128, BK=64, double-buffered, fp32-B direct -------
// grid 512 blocks (1-D, XCD-swizzled: xcd = bid&7 owns mtiles [8*xcd, 8*xcd+8) x all 8 ntiles).
// A (inter bf16): async16 -> linear chunk-layout LDS (global side pre-swizzled), as before.
// B (down fp32 [I,H], K=I rows contiguous in N): reg-staged per K-tile:
//   thread t: n = (t&63)*2 (+1), kg in {t>>6, (t>>6)+4}; loads 16x float2 (512B dense/instr),
//   cvt to bf16, 4x ds_write_b128 into chunk-swizzled [n][k] rows: addr n*64 + (kg^(n&7))*8.
//   Read/fragment path is unchanged from the verified kernel.
// T14 ordering: loads(k+1) issued BEFORE compute(k); cvt+ds_write after; one barrier/step.
__global__ __launch_bounds__(256, 2) void gemm3_k(
    const u16* __restrict__ A, const float* __restrict__ Dw,
    const int* __restrict__ tpe, float* __restrict__ out) {
  __shared__ u16 sA[2][128 * 64];  // 16 KB x2
  __shared__ u16 sB[2][128 * 64];  // 16 KB x2 (bf16, chunk-swizzled [n][k])
  const int t = threadIdx.x;

  // XCD swizzle: 512 blocks, 512 % 8 == 0 -> simple bijective remap.
  const int bid = blockIdx.x;
  const int g = (bid & 7) * 64 + (bid >> 3);
  const int m0 = (g >> 3) * 128;   // 64 M tiles
  const int n0 = (g & 7) * 128;    // 8 N tiles

  int e = 0, seg_end = T_;
  {
    int s = 0;
    for (int i = 0; i < E_; ++i) {
      int c = tpe[i];
      if (m0 < s + c) { e = i; seg_end = s + c; break; }
      s += c;
    }
  }
  const float* De = Dw + (size_t)e * I_ * H_;

  // A staging (unchanged): pre-swizzled global source, linear LDS dest.
  const int sj = ((t & 7) ^ ((t >> 3) & 7)) * 8;
  const u16* gA = A + (size_t)(m0 + (t >> 3)) * I_ + sj;
  const int toff = t * 8;

  // B reg-staging geometry.
  const int bn = (t & 63) * 2;        // even output-row (n) this thread owns (+1)
  const int kg0 = t >> 6;             // k-chunk base (0..3); second is kg0+4
  const float* gBn = De + n0 + bn;    // column base; row k adds k*H_
  const int ch0a = kg0 ^ (bn & 7);          // chunk for row bn, kg0
  const int ch0b = (kg0 + 4) ^ (bn & 7);    // chunk for row bn, kg0+4

  const int l = t & 63, w = t >> 6;
  const int wm = (w & 1) * 64, wn = (w >> 1) * 64;
  const int c0 = (((l >> 4) ^ (l & 7))) * 8;
  const int foff = (wm + (l & 15)) * 64;
  const int goff = (wn + (l & 15)) * 64;

  f32x4 acc[4][4];
#pragma unroll
  for (int mi = 0; mi < 4; ++mi)
#pragma unroll
    for (int ni = 0; ni < 4; ++ni) acc[mi][ni] = (f32x4){0.f, 0.f, 0.f, 0.f};

  float2 fx[2][8];

#define LOADB(k0)                                                          \
  {                                                                        \
    _Pragma("unroll")                                                      \
    for (int i = 0; i < 2; ++i) {                                          \
      const int kb = (k0) + (kg0 + 4 * i) * 8;                             \
      _Pragma("unroll")                                                    \
      for (int j = 0; j < 8; ++j)                                          \
        fx[i][j] = *(const float2*)(gBn + (size_t)(kb + j) * H_);          \
    }                                                                      \
  }

#define WRITEB(buf)                                                        \
  {                                                                        \
    _Pragma("unroll")                                                      \
    for (int i = 0; i < 2; ++i) {                                          \
      u16x8 w0, w1;                                                        \
      _Pragma("unroll")                                                    \
      for (int j = 0; j < 8; ++j) {                                        \
        w0[j] = f2b(fx[i][j].x);                                           \
        w1[j] = f2b(fx[i][j].y);                                           \
      }                                                                    \
      const int ch = (i == 0) ? ch0a : ch0b;                               \
      u16* base = &sB[buf][0] + bn * 64;                                   \
      *(u16x8*)(base + ch * 8) = w0;                                       \
      *(u16x8*)(base + 64 + (ch ^ 1) * 8) = w1;                            \
    }                                                                      \
  }

#define STAGEA(buf, k0)                                                    \
  {                                                                        \
    u16* dA = &sA[buf][0] + toff;                                          \
    async16(gA + (k0), dA);                                                \
    async16(gA + 32 * I_ + (k0), dA + 2048);                               \
    async16(gA + 64 * I_ + (k0), dA + 4096);                               \
    async16(gA + 96 * I_ + (k0), dA + 6144);                               \
  }

  // prologue
  LOADB(0);
  STAGEA(0, 0);
  WRITEB(0);
  __syncthreads();

  int cur = 0;
  for (int k0 = 0; k0 < I_; k0 += 64) {
    const bool hasNext = (k0 + 64 < I_);
    if (hasNext) {
      LOADB(k0 + 64);
      STAGEA(cur ^ 1, k0 + 64);
    }
    const u16* fA = &sA[cur][0] + foff;
    const u16* fB = &sB[cur][0] + goff;
#pragma unroll
    for (int ks = 0; ks < 2; ++ks) {
      const int co = c0 ^ (ks * 32);
      s16x8 aF[4], bF[4];
#pragma unroll
      for (int mi = 0; mi < 4; ++mi) aF[mi] = *(const s16x8*)(fA + mi * 1024 + co);
#pragma unroll
      for (int ni = 0; ni < 4; ++ni) bF[ni] = *(const s16x8*)(fB + ni * 1024 + co);
#pragma unroll
      for (int mi = 0; mi < 4; ++mi)
#pragma unroll
        for (int ni = 0; ni < 4; ++ni)
          acc[mi][ni] = __builtin_amdgcn_mfma_f32_16x16x32_bf16(aF[mi], bF[ni], acc[mi][ni], 0, 0, 0);
    }
    if (hasNext) WRITEB(cur ^ 1);
    __syncthreads();
    cur ^= 1;
  }
#undef LOADB
#undef WRITEB
#undef STAGEA

  const int colb = l & 15, rowb = (l >> 4) * 4;
#pragma unroll
  for (int mi = 0; mi < 4; ++mi)
#pragma unroll
    for (int ni = 0; ni < 4; ++ni) {
      const size_t gcol = (size_t)(n0 + wn + ni * 16 + colb);
#pragma unroll
      for (int r = 0; r < 4; ++r) {
        int grow = m0 + wm + mi * 16 + rowb + r;
        if (grow < seg_end) out[(size_t)grow * H_ + gcol] = acc[mi][ni][r];
      }
    }
}

extern "C" void kernel_launch(void* const* d_in, const int* in_sizes, int n_in,
                              void* d_out, int out_size, void* d_ws, size_t ws_size,
                              hipStream_t stream) {
  const float* X = (const float*)d_in[0];
  const float* G = (const float*)d_in[1];
  const float* U = (const float*)d_in[2];
  const float* D = (const float*)d_in[3];
  const int* tpe = (const int*)d_in[4];
  float* out = (float*)d_out;

  const size_t W = (size_t)E_ * H_ * I_;
  if (ws_size < 3 * W * sizeof(u16)) return;
  u16* r0 = (u16*)d_ws;   // gateT
  u16* r1 = r0 + W;       // upT
  u16* r2 = r1 + W;       // inter [T][I] bf16
  u16* xb = (u16*)d_out;  // bf16 X staged in d_out; dead after gemm12; gemm3 overwrites

  prep_k<<<dim3(4096 + 11264), 256, 0, stream>>>(X, G, U, xb, r0, r1);
  gemm12_k<<<dim3(I_ / 64, T_ / 128), 256, 0, stream>>>(xb, r0, r1, tpe, r2);
  gemm3_k<<<dim3(512), 256, 0, stream>>>(r2, D, tpe, out);
}